// Round 6
// baseline (328.515 us; speedup 1.0000x reference)
//
#include <hip/hip_runtime.h>
#include <hip/hip_fp16.h>

#define BB 4
#define HH 192
#define WW 640
#define CC 32
#define SS 32
#define PXB 64   // pixels per block (one row segment; 640 % 64 == 0)
#define SPH 8    // steps per phase (4 phases x 8 = 32)

typedef _Float16 half2n __attribute__((ext_vector_type(2)));

#if defined(__has_builtin)
#if __has_builtin(__builtin_amdgcn_fdot2)
#define HAS_FDOT2 1
#endif
#endif

// x (fp32, 63MB) -> fp16 copy in workspace (31.5MB). Re-run every call.
__global__ __launch_bounds__(256) void convert_x_kernel(const float* __restrict__ x,
                                                        __half* __restrict__ xh) {
    const size_t i = ((size_t)blockIdx.x * 256 + threadIdx.x) * 8;
    const float4 f0 = *(const float4*)(x + i);
    const float4 f1 = *(const float4*)(x + i + 4);
    uint4 u;
    u.x = __builtin_bit_cast(unsigned, __floats2half2_rn(f0.x, f0.y));
    u.y = __builtin_bit_cast(unsigned, __floats2half2_rn(f0.z, f0.w));
    u.z = __builtin_bit_cast(unsigned, __floats2half2_rn(f1.x, f1.y));
    u.w = __builtin_bit_cast(unsigned, __floats2half2_rn(f1.z, f1.w));
    *(uint4*)(xh + i) = u;
}

// Wave = 16 pixel-slots x 4 channel-lanes (8 fp16 channels each).
// R6: R5's 2-deep corner-load pipeline + full occupancy. R5 showed the
// pipeline gives x1.27 per-wave but launch_bounds(256,6) threw away the
// same factor in waves/CU. 40 VGPR fits 8 waves/EU: take both.
__global__ __launch_bounds__(256, 8) void corr_kernel(
    const __half* __restrict__ xh, const float* __restrict__ y,
    const float* __restrict__ origin, const float* __restrict__ focal,
    const float* __restrict__ T12, float* __restrict__ out)
{
    __shared__ uint4 sOff[SPH * PXB];  // 4 corner byte-offsets
    __shared__ uint4 sWt [SPH * PXB];  // 4 corner weights, each packed half2(w,w)

    const int tid  = threadIdx.x;
    const int lane = tid & 63;
    const int wave = tid >> 6;
    const int slot = lane >> 2;   // pixel within wave (0..15)
    const int cg   = lane & 3;    // channel group: fp16 channels [8cg, 8cg+8)

    const int p0 = blockIdx.x * PXB;
    const int w0 = p0 % WW;
    const int h  = (p0 / WW) % HH;
    const int b  = p0 / (WW * HH);

    const float tz = T12[b * 3 + 2];
    const float kx = tz * origin[b * 2 + 0] + focal[b * 2 + 0] * T12[b * 3 + 0];
    const float ky = tz * origin[b * 2 + 1] + focal[b * 2 + 1] * T12[b * 3 + 1];

    const int pme = p0 + wave * 16 + slot;
    // This lane's 8 y channels as 4 x half2
    __half2 yh[4];
    {
        const float4 ya = *(const float4*)(y + (size_t)pme * CC + cg * 8);
        const float4 yb = *(const float4*)(y + (size_t)pme * CC + cg * 8 + 4);
        yh[0] = __floats2half2_rn(ya.x, ya.y);
        yh[1] = __floats2half2_rn(ya.z, ya.w);
        yh[2] = __floats2half2_rn(yb.x, yb.y);
        yh[3] = __floats2half2_rn(yb.z, yb.w);
    }

    const char* xbase = (const char*)(xh + (size_t)b * HH * WW * CC);
    const int cgb = cg * 16;   // byte offset of channel group within 64B pixel
    const int sp  = wave * 16 + slot;

    // Phase-1 ownership: thread owns (e_px = tid&63, s_loc = tid>>6 and +4)
    const int e_px = tid & 63;
    const int e_s0 = tid >> 6;
    const float ewf = (float)(w0 + e_px);
    const float ehf = (float)h;

    float* outp = out + (size_t)pme * SS;

#pragma unroll 1
    for (int ph = 0; ph < 4; ++ph) {
        __syncthreads();
#pragma unroll
        for (int k = 0; k < 2; ++k) {
            const int s_loc = e_s0 + k * 4;
            const int s = ph * SPH + s_loc;
            const float sf = (float)s;
            // D = 1/(1/s + tz) = s/(1+s*tz); s=0 -> D=0 automatically.
            const float D = sf * __builtin_amdgcn_rcpf(1.0f + sf * tz);
            const float alpha = 1.0f - D * tz;
            const float sx = alpha * ewf + D * kx;
            const float sy = alpha * ehf + D * ky;

            const float x0f = floorf(sx);
            const float y0f = floorf(sy);
            const float fx = sx - x0f;
            const float fy = sy - y0f;
            const int x0 = (int)x0f;
            const int y0 = (int)y0f;
            const int x1 = x0 + 1;
            const int y1 = y0 + 1;

            const float wx0 = (x0 >= 0 && x0 < WW) ? (1.0f - fx) : 0.0f;
            const float wx1 = (x1 >= 0 && x1 < WW) ? fx : 0.0f;
            const float wy0 = (y0 >= 0 && y0 < HH) ? (1.0f - fy) : 0.0f;
            const float wy1 = (y1 >= 0 && y1 < HH) ? fy : 0.0f;

            const int cx0 = min(max(x0, 0), WW - 1);
            const int cx1 = min(max(x1, 0), WW - 1);
            const int cy0 = min(max(y0, 0), HH - 1);
            const int cy1 = min(max(y1, 0), HH - 1);

            const int r0 = cy0 * WW;
            const int r1 = cy1 * WW;
            // fp16 pixel record = 64B -> byte offset = (row*W+col) << 6
            const uint4 offs = make_uint4((unsigned)((r0 + cx0) << 6),
                                          (unsigned)((r0 + cx1) << 6),
                                          (unsigned)((r1 + cx0) << 6),
                                          (unsigned)((r1 + cx1) << 6));
            auto pk = [](float wgt) -> unsigned {
                const unsigned short us =
                    __builtin_bit_cast(unsigned short, __float2half_rn(wgt));
                return (unsigned)us * 0x10001u;   // half2(w, w)
            };
            const uint4 wts = make_uint4(pk(wy0 * wx0), pk(wy0 * wx1),
                                         pk(wy1 * wx0), pk(wy1 * wx1));
            sOff[s_loc * PXB + e_px] = offs;
            sWt [s_loc * PXB + e_px] = wts;
        }
        __syncthreads();

        float res0 = 0.0f, res1 = 0.0f;

        // ---- software pipeline: prologue (step 0 of this phase) ----
        uint4 o  = sOff[sp];
        uint4 wt = sWt [sp];
        uint4 ua = *(const uint4*)(xbase + (size_t)(o.x + cgb));
        uint4 ub = *(const uint4*)(xbase + (size_t)(o.y + cgb));
        uint4 uc = *(const uint4*)(xbase + (size_t)(o.z + cgb));
        uint4 ud = *(const uint4*)(xbase + (size_t)(o.w + cgb));

#pragma unroll
        for (int j = 0; j < SPH; ++j) {
            uint4 o2, wt2, na, nb, nc, nd;
            if (j + 1 < SPH) {
                // issue next step's loads BEFORE consuming current registers
                o2  = sOff[(j + 1) * PXB + sp];
                wt2 = sWt [(j + 1) * PXB + sp];
                na = *(const uint4*)(xbase + (size_t)(o2.x + cgb));
                nb = *(const uint4*)(xbase + (size_t)(o2.y + cgb));
                nc = *(const uint4*)(xbase + (size_t)(o2.z + cgb));
                nd = *(const uint4*)(xbase + (size_t)(o2.w + cgb));
            }

            const __half2 w00 = __builtin_bit_cast(__half2, wt.x);
            const __half2 w01 = __builtin_bit_cast(__half2, wt.y);
            const __half2 w10 = __builtin_bit_cast(__half2, wt.z);
            const __half2 w11 = __builtin_bit_cast(__half2, wt.w);

            float acc = 0.0f;
#pragma unroll
            for (int i = 0; i < 4; ++i) {
                const unsigned va = (&ua.x)[i];
                const unsigned vb = (&ub.x)[i];
                const unsigned vc = (&uc.x)[i];
                const unsigned vd = (&ud.x)[i];
                __half2 comb = __hmul2(__builtin_bit_cast(__half2, va), w00);
                comb = __hfma2(__builtin_bit_cast(__half2, vb), w01, comb);
                comb = __hfma2(__builtin_bit_cast(__half2, vc), w10, comb);
                comb = __hfma2(__builtin_bit_cast(__half2, vd), w11, comb);
#ifdef HAS_FDOT2
                acc = __builtin_amdgcn_fdot2(__builtin_bit_cast(half2n, comb),
                                             __builtin_bit_cast(half2n, yh[i]),
                                             acc, false);
#else
                const float2 cf = __half22float2(comb);
                const float2 yf = __half22float2(yh[i]);
                acc += cf.x * yf.x + cf.y * yf.y;
#endif
            }

            // Reduce over the 4 channel-lanes (hardware quad -> DPP quad_perm).
            acc += __shfl_xor(acc, 1, 64);
            acc += __shfl_xor(acc, 2, 64);

            if ((j & 3) == cg) {
                if (j < 4) res0 = acc * (1.0f / 32.0f);
                else       res1 = acc * (1.0f / 32.0f);
            }

            if (j + 1 < SPH) {  // rotate pipeline registers (SSA under unroll)
                o = o2; wt = wt2; ua = na; ub = nb; uc = nc; ud = nd;
            }
        }
        outp[ph * SPH + cg]     = res0;
        outp[ph * SPH + 4 + cg] = res1;
    }
}

extern "C" void kernel_launch(void* const* d_in, const int* in_sizes, int n_in,
                              void* d_out, int out_size, void* d_ws, size_t ws_size,
                              hipStream_t stream) {
    const float* x = (const float*)d_in[0];
    const float* y = (const float*)d_in[1];
    const float* origin = (const float*)d_in[2];
    const float* focal = (const float*)d_in[3];
    const float* T12 = (const float*)d_in[4];
    float* out = (float*)d_out;
    __half* xh = (__half*)d_ws;   // needs BB*HH*WW*CC*2 = 31.5 MB

    const int nelem = BB * HH * WW * CC;          // 15,728,640
    convert_x_kernel<<<nelem / (256 * 8), 256, 0, stream>>>(x, xh);

    const int npix = BB * HH * WW;                // 491,520
    corr_kernel<<<npix / PXB, 256, 0, stream>>>(xh, y, origin, focal, T12, out);
}

// Round 7
// 306.241 us; speedup vs baseline: 1.0727x; 1.0727x over previous
//
#include <hip/hip_runtime.h>
#include <hip/hip_fp16.h>

#define BB 4
#define HH 192
#define WW 640
#define CC 32
#define SS 32
#define PXB 64   // pixels per block (one row segment; 640 % 64 == 0)
#define SPH 8    // steps per phase (4 phases x 8 = 32)

typedef _Float16 half2n __attribute__((ext_vector_type(2)));

#if defined(__has_builtin)
#if __has_builtin(__builtin_amdgcn_fdot2)
#define HAS_FDOT2 1
#endif
#endif

// x (fp32, 63MB) -> fp16 copy in workspace (31.5MB). Re-run every call.
__global__ __launch_bounds__(256) void convert_x_kernel(const float* __restrict__ x,
                                                        __half* __restrict__ xh) {
    const size_t i = ((size_t)blockIdx.x * 256 + threadIdx.x) * 8;
    const float4 f0 = *(const float4*)(x + i);
    const float4 f1 = *(const float4*)(x + i + 4);
    uint4 u;
    u.x = __builtin_bit_cast(unsigned, __floats2half2_rn(f0.x, f0.y));
    u.y = __builtin_bit_cast(unsigned, __floats2half2_rn(f0.z, f0.w));
    u.z = __builtin_bit_cast(unsigned, __floats2half2_rn(f1.x, f1.y));
    u.w = __builtin_bit_cast(unsigned, __floats2half2_rn(f1.z, f1.w));
    *(uint4*)(xh + i) = u;
}

// Wave = 16 pixel-slots x 4 channel-lanes (8 fp16 channels each).
// R7: R5's 2-deep corner-load pipeline (40 VGPR schedule) at (256,7):
// VGPR cap 73 leaves the pipeline intact (R6's (256,8) cap squeezed it to
// 32 VGPR and regressed), while allowing 28 waves/CU vs R5's 20.5.
__global__ __launch_bounds__(256, 7) void corr_kernel(
    const __half* __restrict__ xh, const float* __restrict__ y,
    const float* __restrict__ origin, const float* __restrict__ focal,
    const float* __restrict__ T12, float* __restrict__ out)
{
    __shared__ uint4 sOff[SPH * PXB];  // 4 corner byte-offsets
    __shared__ uint4 sWt [SPH * PXB];  // 4 corner weights, each packed half2(w,w)

    const int tid  = threadIdx.x;
    const int lane = tid & 63;
    const int wave = tid >> 6;
    const int slot = lane >> 2;   // pixel within wave (0..15)
    const int cg   = lane & 3;    // channel group: fp16 channels [8cg, 8cg+8)

    const int p0 = blockIdx.x * PXB;
    const int w0 = p0 % WW;
    const int h  = (p0 / WW) % HH;
    const int b  = p0 / (WW * HH);

    const float tz = T12[b * 3 + 2];
    const float kx = tz * origin[b * 2 + 0] + focal[b * 2 + 0] * T12[b * 3 + 0];
    const float ky = tz * origin[b * 2 + 1] + focal[b * 2 + 1] * T12[b * 3 + 1];

    const int pme = p0 + wave * 16 + slot;
    // This lane's 8 y channels as 4 x half2
    __half2 yh[4];
    {
        const float4 ya = *(const float4*)(y + (size_t)pme * CC + cg * 8);
        const float4 yb = *(const float4*)(y + (size_t)pme * CC + cg * 8 + 4);
        yh[0] = __floats2half2_rn(ya.x, ya.y);
        yh[1] = __floats2half2_rn(ya.z, ya.w);
        yh[2] = __floats2half2_rn(yb.x, yb.y);
        yh[3] = __floats2half2_rn(yb.z, yb.w);
    }

    const char* xbase = (const char*)(xh + (size_t)b * HH * WW * CC);
    const int cgb = cg * 16;   // byte offset of channel group within 64B pixel
    const int sp  = wave * 16 + slot;

    // Phase-1 ownership: thread owns (e_px = tid&63, s_loc = tid>>6 and +4)
    const int e_px = tid & 63;
    const int e_s0 = tid >> 6;
    const float ewf = (float)(w0 + e_px);
    const float ehf = (float)h;

    float* outp = out + (size_t)pme * SS;

#pragma unroll 1
    for (int ph = 0; ph < 4; ++ph) {
        __syncthreads();
#pragma unroll
        for (int k = 0; k < 2; ++k) {
            const int s_loc = e_s0 + k * 4;
            const int s = ph * SPH + s_loc;
            const float sf = (float)s;
            // D = 1/(1/s + tz) = s/(1+s*tz); s=0 -> D=0 automatically.
            const float D = sf * __builtin_amdgcn_rcpf(1.0f + sf * tz);
            const float alpha = 1.0f - D * tz;
            const float sx = alpha * ewf + D * kx;
            const float sy = alpha * ehf + D * ky;

            const float x0f = floorf(sx);
            const float y0f = floorf(sy);
            const float fx = sx - x0f;
            const float fy = sy - y0f;
            const int x0 = (int)x0f;
            const int y0 = (int)y0f;
            const int x1 = x0 + 1;
            const int y1 = y0 + 1;

            const float wx0 = (x0 >= 0 && x0 < WW) ? (1.0f - fx) : 0.0f;
            const float wx1 = (x1 >= 0 && x1 < WW) ? fx : 0.0f;
            const float wy0 = (y0 >= 0 && y0 < HH) ? (1.0f - fy) : 0.0f;
            const float wy1 = (y1 >= 0 && y1 < HH) ? fy : 0.0f;

            const int cx0 = min(max(x0, 0), WW - 1);
            const int cx1 = min(max(x1, 0), WW - 1);
            const int cy0 = min(max(y0, 0), HH - 1);
            const int cy1 = min(max(y1, 0), HH - 1);

            const int r0 = cy0 * WW;
            const int r1 = cy1 * WW;
            // fp16 pixel record = 64B -> byte offset = (row*W+col) << 6
            const uint4 offs = make_uint4((unsigned)((r0 + cx0) << 6),
                                          (unsigned)((r0 + cx1) << 6),
                                          (unsigned)((r1 + cx0) << 6),
                                          (unsigned)((r1 + cx1) << 6));
            auto pk = [](float wgt) -> unsigned {
                const unsigned short us =
                    __builtin_bit_cast(unsigned short, __float2half_rn(wgt));
                return (unsigned)us * 0x10001u;   // half2(w, w)
            };
            const uint4 wts = make_uint4(pk(wy0 * wx0), pk(wy0 * wx1),
                                         pk(wy1 * wx0), pk(wy1 * wx1));
            sOff[s_loc * PXB + e_px] = offs;
            sWt [s_loc * PXB + e_px] = wts;
        }
        __syncthreads();

        float res0 = 0.0f, res1 = 0.0f;

        // ---- software pipeline: prologue (step 0 of this phase) ----
        uint4 o  = sOff[sp];
        uint4 wt = sWt [sp];
        uint4 ua = *(const uint4*)(xbase + (size_t)(o.x + cgb));
        uint4 ub = *(const uint4*)(xbase + (size_t)(o.y + cgb));
        uint4 uc = *(const uint4*)(xbase + (size_t)(o.z + cgb));
        uint4 ud = *(const uint4*)(xbase + (size_t)(o.w + cgb));

#pragma unroll
        for (int j = 0; j < SPH; ++j) {
            uint4 o2, wt2, na, nb, nc, nd;
            if (j + 1 < SPH) {
                // issue next step's loads BEFORE consuming current registers
                o2  = sOff[(j + 1) * PXB + sp];
                wt2 = sWt [(j + 1) * PXB + sp];
                na = *(const uint4*)(xbase + (size_t)(o2.x + cgb));
                nb = *(const uint4*)(xbase + (size_t)(o2.y + cgb));
                nc = *(const uint4*)(xbase + (size_t)(o2.z + cgb));
                nd = *(const uint4*)(xbase + (size_t)(o2.w + cgb));
            }

            const __half2 w00 = __builtin_bit_cast(__half2, wt.x);
            const __half2 w01 = __builtin_bit_cast(__half2, wt.y);
            const __half2 w10 = __builtin_bit_cast(__half2, wt.z);
            const __half2 w11 = __builtin_bit_cast(__half2, wt.w);

            float acc = 0.0f;
#pragma unroll
            for (int i = 0; i < 4; ++i) {
                const unsigned va = (&ua.x)[i];
                const unsigned vb = (&ub.x)[i];
                const unsigned vc = (&uc.x)[i];
                const unsigned vd = (&ud.x)[i];
                __half2 comb = __hmul2(__builtin_bit_cast(__half2, va), w00);
                comb = __hfma2(__builtin_bit_cast(__half2, vb), w01, comb);
                comb = __hfma2(__builtin_bit_cast(__half2, vc), w10, comb);
                comb = __hfma2(__builtin_bit_cast(__half2, vd), w11, comb);
#ifdef HAS_FDOT2
                acc = __builtin_amdgcn_fdot2(__builtin_bit_cast(half2n, comb),
                                             __builtin_bit_cast(half2n, yh[i]),
                                             acc, false);
#else
                const float2 cf = __half22float2(comb);
                const float2 yf = __half22float2(yh[i]);
                acc += cf.x * yf.x + cf.y * yf.y;
#endif
            }

            // Reduce over the 4 channel-lanes (hardware quad -> DPP quad_perm).
            acc += __shfl_xor(acc, 1, 64);
            acc += __shfl_xor(acc, 2, 64);

            if ((j & 3) == cg) {
                if (j < 4) res0 = acc * (1.0f / 32.0f);
                else       res1 = acc * (1.0f / 32.0f);
            }

            if (j + 1 < SPH) {  // rotate pipeline registers (SSA under unroll)
                o = o2; wt = wt2; ua = na; ub = nb; uc = nc; ud = nd;
            }
        }
        outp[ph * SPH + cg]     = res0;
        outp[ph * SPH + 4 + cg] = res1;
    }
}

extern "C" void kernel_launch(void* const* d_in, const int* in_sizes, int n_in,
                              void* d_out, int out_size, void* d_ws, size_t ws_size,
                              hipStream_t stream) {
    const float* x = (const float*)d_in[0];
    const float* y = (const float*)d_in[1];
    const float* origin = (const float*)d_in[2];
    const float* focal = (const float*)d_in[3];
    const float* T12 = (const float*)d_in[4];
    float* out = (float*)d_out;
    __half* xh = (__half*)d_ws;   // needs BB*HH*WW*CC*2 = 31.5 MB

    const int nelem = BB * HH * WW * CC;          // 15,728,640
    convert_x_kernel<<<nelem / (256 * 8), 256, 0, stream>>>(x, xh);

    const int npix = BB * HH * WW;                // 491,520
    corr_kernel<<<npix / PXB, 256, 0, stream>>>(xh, y, origin, focal, T12, out);
}